// Round 1
// baseline (828.451 us; speedup 1.0000x reference)
//
#include <hip/hip_runtime.h>

// CRF forward: B=256 batches, T<=2048, C=64 classes.
// One wave (64 lanes) per batch; lane j owns class j.
// alpha_t[j] = x[t][j] + m + ln( sum_k E[j][k] * exp(alpha_{t-1}[k] - m) )
// with E = exp(transitions) precomputed in registers and m = alpha[lane 0]
// (valid shift: |alpha[j]-alpha[0]| <= ~13 given trans in [0,1], x ~ N(0,1)).

#define CC 64

__launch_bounds__(64, 1)
__global__ void crf_fwd_kernel(const float* __restrict__ x,      // (B,T,C)
                               const float* __restrict__ trans,  // (C,C)
                               const float* __restrict__ orig,   // (C,)
                               const int*   __restrict__ lens,   // (B,)
                               float* __restrict__ out,          // (B,)
                               int T) {
    const int b = blockIdx.x;
    const int j = threadIdx.x;  // class index 0..63

    // ping-pong p buffers (avoid WAR barrier between iterations)
    __shared__ float p_lds[2][CC];

    // E[j][k] = exp(trans[j][k]) -> 64 VGPRs on lane j
    float E[CC];
    {
        const float4* tr4 = reinterpret_cast<const float4*>(trans + j * CC);
        #pragma unroll
        for (int k4 = 0; k4 < CC / 4; ++k4) {
            float4 v = tr4[k4];
            E[4 * k4 + 0] = __expf(v.x);
            E[4 * k4 + 1] = __expf(v.y);
            E[4 * k4 + 2] = __expf(v.z);
            E[4 * k4 + 3] = __expf(v.w);
        }
    }

    const int L = lens[b];
    const float* xb = x + (size_t)b * T * CC + j;

    // alpha_0
    float alpha = xb[0] + orig[j];

    // 2-deep x prefetch pipeline
    float x1 = (1 < L) ? xb[(size_t)1 * CC] : 0.f;
    float x2 = (2 < L) ? xb[(size_t)2 * CC] : 0.f;

    int buf = 0;
    for (int t = 1; t < L; ++t) {
        // prefetch x[t+2]
        float xpf = (t + 2 < L) ? xb[(size_t)(t + 2) * CC] : 0.f;

        // wave-uniform logsumexp shift (lane 0's alpha; within 13 of true max)
        float m = __int_as_float(__builtin_amdgcn_readfirstlane(__float_as_int(alpha)));
        float p = __expf(alpha - m);

        p_lds[buf][j] = p;
        __syncthreads();  // single wave: compiles to a waitcnt, ~free

        const float4* p4 = reinterpret_cast<const float4*>(p_lds[buf]);
        float acc0 = 0.f, acc1 = 0.f, acc2 = 0.f, acc3 = 0.f;
        #pragma unroll
        for (int k4 = 0; k4 < CC / 4; ++k4) {
            float4 pv = p4[k4];  // broadcast read, conflict-free
            acc0 = fmaf(E[4 * k4 + 0], pv.x, acc0);
            acc1 = fmaf(E[4 * k4 + 1], pv.y, acc1);
            acc2 = fmaf(E[4 * k4 + 2], pv.z, acc2);
            acc3 = fmaf(E[4 * k4 + 3], pv.w, acc3);
        }
        float s = (acc0 + acc1) + (acc2 + acc3);

        alpha = x1 + m + __logf(s);

        x1 = x2;
        x2 = xpf;
        buf ^= 1;
    }

    // out[b] = sum_j alpha[j]  (plain sum, per reference)
    float v = alpha;
    #pragma unroll
    for (int off = 32; off; off >>= 1) v += __shfl_xor(v, off, 64);
    if (j == 0) out[b] = v;
}

extern "C" void kernel_launch(void* const* d_in, const int* in_sizes, int n_in,
                              void* d_out, int out_size, void* d_ws, size_t ws_size,
                              hipStream_t stream) {
    const float* x     = (const float*)d_in[0];  // (B,T,C) fp32
    const float* trans = (const float*)d_in[1];  // (C,C)   fp32
    const float* orig  = (const float*)d_in[2];  // (C,)    fp32
    const int*   lens  = (const int*)d_in[3];    // (B,)    int32
    float* out = (float*)d_out;

    const int B = in_sizes[3];
    const int T = in_sizes[0] / (B * CC);

    crf_fwd_kernel<<<B, CC, 0, stream>>>(x, trans, orig, lens, out, T);
}

// Round 2
// 661.399 us; speedup vs baseline: 1.2526x; 1.2526x over previous
//
#include <hip/hip_runtime.h>

// CRF forward: B=256 batches, T<=2048, C=64. One wave per batch, lane j = class j.
// Linear-space recurrence with deferred uniform renormalization:
//   q_t[j]   = exp2(x_t[j]*log2e) * S_t[j] * r        (S_t = E . q_{t-1}, E = exp(trans))
//   r        = rcp(firstlane(S_{t-1}))                 (wave-uniform, off critical path)
//   Mbar    -= log2(r_applied)                         (exact shift bookkeeping, off path)
//   alpha_t[j] = ln2 * (Mbar + log2(q_t[j]))
// No barriers (single wave): LDS write->read ordered by inline s_waitcnt lgkmcnt(0),
// so the 8-deep global x prefetch is never drained.

#define CC 64
#define PF 8

__device__ __forceinline__ float bcast0(float v) {
    return __int_as_float(__builtin_amdgcn_readfirstlane(__float_as_int(v)));
}

#define LDS_FENCE() asm volatile("s_waitcnt lgkmcnt(0)" ::: "memory")

__launch_bounds__(64, 1)
__global__ void crf_fwd_kernel(const float* __restrict__ x,      // (B,T,C)
                               const float* __restrict__ trans,  // (C,C)
                               const float* __restrict__ orig,   // (C,)
                               const int*   __restrict__ lens,   // (B,)
                               float* __restrict__ out,          // (B,)
                               int T) {
    const int b = blockIdx.x;
    const int j = threadIdx.x;  // class 0..63

    __shared__ float q_lds[2][CC];

    const float LOG2E = 1.4426950408889634f;
    const float LN2   = 0.6931471805599453f;

    // E[k] = exp(trans[j][k])  (row j in lane j's registers)
    float E[CC];
    {
        const float4* tr4 = reinterpret_cast<const float4*>(trans + j * CC);
        #pragma unroll
        for (int k4 = 0; k4 < CC / 4; ++k4) {
            float4 v = tr4[k4];
            E[4 * k4 + 0] = __builtin_amdgcn_exp2f(v.x * LOG2E);
            E[4 * k4 + 1] = __builtin_amdgcn_exp2f(v.y * LOG2E);
            E[4 * k4 + 2] = __builtin_amdgcn_exp2f(v.z * LOG2E);
            E[4 * k4 + 3] = __builtin_amdgcn_exp2f(v.w * LOG2E);
        }
    }

    const int L = lens[b];
    const float* xb = x + (size_t)b * T * CC + j;

    // alpha_0 in base-2 log space; shift = lane0's value (spread bounded ~13 nats)
    float a0   = (xb[0] + orig[j]) * LOG2E;
    float Mbar = bcast0(a0);
    float q    = __builtin_amdgcn_exp2f(a0 - Mbar);

    q_lds[0][j] = q;
    LDS_FENCE();

    // 8-deep x prefetch ring (static indices only)
    float XP[PF];
    #pragma unroll
    for (int u = 0; u < PF; ++u) {
        int tp = 1 + u; if (tp > T - 1) tp = T - 1;
        XP[u] = xb[(size_t)tp * CC];
    }

    float r = 1.0f, lgr = 0.0f;  // renorm scale applied this step + its exact log2

    int t0 = 1;
    for (; t0 + (PF - 1) < L; t0 += PF) {
        #pragma unroll
        for (int u = 0; u < PF; ++u) {
            const int t = t0 + u;  // t0 odd -> (t-1)&1 == u&1

            float xv = XP[u];                       // waits vmcnt for 8-step-old load
            int tp = t + PF; if (tp > T - 1) tp = T - 1;
            XP[u] = xb[(size_t)tp * CC];            // refill ring (in flight 8 steps)

            float ex  = __builtin_amdgcn_exp2f(xv * LOG2E);  // off critical path
            float exr = ex * r;                              // fold renorm early

            // S = E . q_prev  (broadcast reads, conflict-free)
            const float4* q4 = reinterpret_cast<const float4*>(q_lds[u & 1]);
            float acc0 = 0.f, acc1 = 0.f, acc2 = 0.f, acc3 = 0.f;
            #pragma unroll
            for (int k4 = 0; k4 < CC / 4; ++k4) {
                float4 pv = q4[k4];
                acc0 = fmaf(E[4 * k4 + 0], pv.x, acc0);
                acc1 = fmaf(E[4 * k4 + 1], pv.y, acc1);
                acc2 = fmaf(E[4 * k4 + 2], pv.z, acc2);
                acc3 = fmaf(E[4 * k4 + 3], pv.w, acc3);
            }
            float S = (acc0 + acc1) + (acc2 + acc3);

            q = exr * S;                            // critical: one mul after S
            q_lds[(u & 1) ^ 1][j] = q;
            LDS_FENCE();

            // off critical path: bookkeeping for next step
            Mbar -= lgr;
            float S0 = bcast0(S);
            r   = __builtin_amdgcn_rcpf(S0);
            lgr = __builtin_amdgcn_logf(r);         // log2 of the ACTUAL scale applied
        }
    }

    // tail (< PF steps)
    for (int t = t0; t < L; ++t) {
        float xv  = xb[(size_t)t * CC];
        float ex  = __builtin_amdgcn_exp2f(xv * LOG2E);
        float exr = ex * r;

        const float4* q4 = reinterpret_cast<const float4*>(q_lds[(t - 1) & 1]);
        float acc0 = 0.f, acc1 = 0.f, acc2 = 0.f, acc3 = 0.f;
        #pragma unroll
        for (int k4 = 0; k4 < CC / 4; ++k4) {
            float4 pv = q4[k4];
            acc0 = fmaf(E[4 * k4 + 0], pv.x, acc0);
            acc1 = fmaf(E[4 * k4 + 1], pv.y, acc1);
            acc2 = fmaf(E[4 * k4 + 2], pv.z, acc2);
            acc3 = fmaf(E[4 * k4 + 3], pv.w, acc3);
        }
        float S = (acc0 + acc1) + (acc2 + acc3);

        q = exr * S;
        q_lds[t & 1][j] = q;
        LDS_FENCE();

        Mbar -= lgr;
        float S0 = bcast0(S);
        r   = __builtin_amdgcn_rcpf(S0);
        lgr = __builtin_amdgcn_logf(r);
    }

    // alpha_{L-1}[j] = ln2 * (Mbar + log2 q_j); out[b] = sum_j alpha
    float alpha = LN2 * (Mbar + __builtin_amdgcn_logf(q));
    #pragma unroll
    for (int off = 32; off; off >>= 1) alpha += __shfl_xor(alpha, off, 64);
    if (j == 0) out[b] = alpha;
}

extern "C" void kernel_launch(void* const* d_in, const int* in_sizes, int n_in,
                              void* d_out, int out_size, void* d_ws, size_t ws_size,
                              hipStream_t stream) {
    const float* x     = (const float*)d_in[0];
    const float* trans = (const float*)d_in[1];
    const float* orig  = (const float*)d_in[2];
    const int*   lens  = (const int*)d_in[3];
    float* out = (float*)d_out;

    const int B = in_sizes[3];
    const int T = in_sizes[0] / (B * CC);

    crf_fwd_kernel<<<B, CC, 0, stream>>>(x, trans, orig, lens, out, T);
}

// Round 4
// 467.958 us; speedup vs baseline: 1.7704x; 1.4134x over previous
//
#include <hip/hip_runtime.h>

// CRF forward: B=256, T<=2048, C=64. One block (4 waves, 256 thr) per batch.
// Per step: S[j] = sum_k E[j][k] * q_prev[k], split as (4 waves x 4 k-quarters):
//   thread (w,l): j = 16w + (l&15), kq = l>>4 -> 16 FMAs over its k-quarter,
//   then reduce across kq groups with __shfl_xor(16) + __shfl_xor(32).
// Renorm: r = rcp(q_prev[0]) (LDS broadcast -> identical on all waves), exact
// shift bookkeeping Mbar -= log2(r). Raw s_barrier (no vmcnt drain) keeps the
// 8-deep global x prefetch in flight across steps.

#define CC 64
#define PF 8

#define WG_SYNC() do {                                      \
    asm volatile("s_waitcnt lgkmcnt(0)" ::: "memory");      \
    __builtin_amdgcn_s_barrier();                           \
    asm volatile("" ::: "memory");                          \
} while (0)

__launch_bounds__(256, 1)
__global__ void crf_fwd_kernel(const float* __restrict__ x,      // (B,T,C)
                               const float* __restrict__ trans,  // (C,C)
                               const float* __restrict__ orig,   // (C,)
                               const int*   __restrict__ lens,   // (B,)
                               float* __restrict__ out,          // (B,)
                               int T) {
    const int b   = blockIdx.x;
    const int tid = threadIdx.x;
    const int w   = tid >> 6;        // wave 0..3
    const int l   = tid & 63;        // lane
    const int c   = l & 15;
    const int j   = (w << 4) | c;    // class this thread produces
    const int kq  = l >> 4;          // k-quarter 0..3

    __shared__ float qbuf[2][CC];
    __shared__ float wpart[4];

    const float LOG2E = 1.4426950408889634f;
    const float LN2   = 0.6931471805599453f;

    // E[i] = 2^(trans[j][16*kq+i] * log2e)  (this thread's k-quarter of row j)
    float E[16];
    {
        const float4* tr4 = reinterpret_cast<const float4*>(trans + j * CC + kq * 16);
        #pragma unroll
        for (int i4 = 0; i4 < 4; ++i4) {
            float4 v = tr4[i4];
            E[4*i4+0] = __builtin_amdgcn_exp2f(v.x * LOG2E);
            E[4*i4+1] = __builtin_amdgcn_exp2f(v.y * LOG2E);
            E[4*i4+2] = __builtin_amdgcn_exp2f(v.z * LOG2E);
            E[4*i4+3] = __builtin_amdgcn_exp2f(v.w * LOG2E);
        }
    }

    const int L = lens[b];
    const float* xb = x + (size_t)b * T * CC;

    // init: base-2 log space, shift = a0_hat[0] (uniform across all threads)
    float a0   = (xb[j] + orig[j]) * LOG2E;
    float Mbar = (xb[0] + orig[0]) * LOG2E;
    float q    = __builtin_amdgcn_exp2f(a0 - Mbar);

    float qk = q, Mk = Mbar;  // value kept at t == L-1 (init covers L == 1)

    if (kq == 0) qbuf[0][j] = q;

    // 8-deep x prefetch ring (static indices only)
    float XP[PF];
    #pragma unroll
    for (int u = 0; u < PF; ++u) {
        int tp = 1 + u; if (tp > T - 1) tp = T - 1;
        XP[u] = xb[(size_t)tp * CC + j];
    }

    WG_SYNC();

    // main loop; last chunk overshoots past L (renormalized, results not kept)
    for (int t0 = 1; t0 < L; t0 += PF) {
        #pragma unroll
        for (int u = 0; u < PF; ++u) {
            const int tt = t0 + u;
            const int pb = (tt - 1) & 1, cb = tt & 1;

            float xv = XP[u];                       // 8-step-old load (vmcnt wait)
            int tp = tt + PF; if (tp > T - 1) tp = T - 1;
            XP[u] = xb[(size_t)tp * CC + j];        // refill ring

            const float4* q4 = reinterpret_cast<const float4*>(&qbuf[pb][kq * 16]);
            float q0p = qbuf[pb][0];                // broadcast read, all waves same
            float r   = __builtin_amdgcn_rcpf(q0p); // wave-uniform renorm scale
            float lgr = __builtin_amdgcn_logf(r);   // log2 of ACTUAL scale (exact bookkeeping)
            float exr = __builtin_amdgcn_exp2f(xv * LOG2E) * r;

            float acc0 = 0.f, acc1 = 0.f, acc2 = 0.f, acc3 = 0.f;
            #pragma unroll
            for (int i4 = 0; i4 < 4; ++i4) {
                float4 pv = q4[i4];
                acc0 = fmaf(E[4*i4+0], pv.x, acc0);
                acc1 = fmaf(E[4*i4+1], pv.y, acc1);
                acc2 = fmaf(E[4*i4+2], pv.z, acc2);
                acc3 = fmaf(E[4*i4+3], pv.w, acc3);
            }
            float v = (acc0 + acc1) + (acc2 + acc3); // partial over this k-quarter
            v += __shfl_xor(v, 16, 64);              // + partner kq^1
            v += __shfl_xor(v, 32, 64);              // + partner kq^2 -> full S[j]

            q = exr * v;
            Mbar -= lgr;
            if (tt == L - 1) { qk = q; Mk = Mbar; }
            if (kq == 0) qbuf[cb][j] = q;

            WG_SYNC();                               // raw: no vmcnt drain
        }
    }

    // alpha[j] at t = L-1; out[b] = sum_j alpha[j]
    float alpha = LN2 * (Mk + __builtin_amdgcn_logf(qk));
    alpha += __shfl_xor(alpha, 1, 64);
    alpha += __shfl_xor(alpha, 2, 64);
    alpha += __shfl_xor(alpha, 4, 64);
    alpha += __shfl_xor(alpha, 8, 64);   // sum over the wave's 16 classes
    if (l == 0) wpart[w] = alpha;
    WG_SYNC();
    if (tid == 0) out[b] = (wpart[0] + wpart[1]) + (wpart[2] + wpart[3]);
}

extern "C" void kernel_launch(void* const* d_in, const int* in_sizes, int n_in,
                              void* d_out, int out_size, void* d_ws, size_t ws_size,
                              hipStream_t stream) {
    const float* x     = (const float*)d_in[0];
    const float* trans = (const float*)d_in[1];
    const float* orig  = (const float*)d_in[2];
    const int*   lens  = (const int*)d_in[3];
    float* out = (float*)d_out;

    const int B = in_sizes[3];
    const int T = in_sizes[0] / (B * CC);

    crf_fwd_kernel<<<B, 256, 0, stream>>>(x, trans, orig, lens, out, T);
}

// Round 5
// 389.705 us; speedup vs baseline: 2.1258x; 1.2008x over previous
//
#include <hip/hip_runtime.h>

// CRF forward: B=256, T<=2048, C=64. One block (4 waves, 256 thr) per batch.
// Per step: S[j] = sum_k E[j][k] * q_prev[k], split as (4 waves x 4 k-quarters):
//   thread (w,l): j = 16w + (l&15), kq = l>>4 -> 16 FMAs over its k-quarter,
//   then kq-reduce with permlane16/32_swap "sum both outputs" (pure VALU):
//   for any complementary swap, swap(v,v) returns per-lane the set
//   {v[l], v[l^G]}, so out0+out1 == v[l] + v[l^G] independent of output order.
// Renorm: r = rcp(q_prev[0]) (LDS broadcast -> identical on all waves), exact
// shift bookkeeping Mbar -= log2(r). Raw s_barrier (no vmcnt drain) keeps the
// 8-deep global x prefetch in flight across steps.

#define CC 64
#define PF 8

#define WG_SYNC() do {                                      \
    asm volatile("s_waitcnt lgkmcnt(0)" ::: "memory");      \
    __builtin_amdgcn_s_barrier();                           \
    asm volatile("" ::: "memory");                          \
} while (0)

__device__ __forceinline__ float pairsum16(float v) {
#if __has_builtin(__builtin_amdgcn_permlane16_swap)
    unsigned u = __float_as_uint(v);
    auto r = __builtin_amdgcn_permlane16_swap(u, u, false, false);
    return __uint_as_float(r[0]) + __uint_as_float(r[1]);
#else
    // ds_swizzle xor-16 within each 32-lane half (BitMode 0x401F)
    return v + __int_as_float(__builtin_amdgcn_ds_swizzle(__float_as_int(v), 0x401F));
#endif
}

__device__ __forceinline__ float pairsum32(float v, int lane) {
#if __has_builtin(__builtin_amdgcn_permlane32_swap)
    unsigned u = __float_as_uint(v);
    auto r = __builtin_amdgcn_permlane32_swap(u, u, false, false);
    return __uint_as_float(r[0]) + __uint_as_float(r[1]);
#else
    int idx = (lane ^ 32) << 2;
    return v + __int_as_float(__builtin_amdgcn_ds_bpermute(idx, __float_as_int(v)));
#endif
}

__launch_bounds__(256, 1)
__global__ void crf_fwd_kernel(const float* __restrict__ x,      // (B,T,C)
                               const float* __restrict__ trans,  // (C,C)
                               const float* __restrict__ orig,   // (C,)
                               const int*   __restrict__ lens,   // (B,)
                               float* __restrict__ out,          // (B,)
                               int T) {
    const int b   = blockIdx.x;
    const int tid = threadIdx.x;
    const int w   = tid >> 6;        // wave 0..3
    const int l   = tid & 63;        // lane
    const int c   = l & 15;
    const int j   = (w << 4) | c;    // class this thread produces
    const int kq  = l >> 4;          // k-quarter 0..3

    __shared__ float qbuf[2][CC];
    __shared__ float wpart[4];

    const float LOG2E = 1.4426950408889634f;
    const float LN2   = 0.6931471805599453f;

    // E[i] = 2^(trans[j][16*kq+i] * log2e)  (this thread's k-quarter of row j)
    float E[16];
    {
        const float4* tr4 = reinterpret_cast<const float4*>(trans + j * CC + kq * 16);
        #pragma unroll
        for (int i4 = 0; i4 < 4; ++i4) {
            float4 v = tr4[i4];
            E[4*i4+0] = __builtin_amdgcn_exp2f(v.x * LOG2E);
            E[4*i4+1] = __builtin_amdgcn_exp2f(v.y * LOG2E);
            E[4*i4+2] = __builtin_amdgcn_exp2f(v.z * LOG2E);
            E[4*i4+3] = __builtin_amdgcn_exp2f(v.w * LOG2E);
        }
    }

    const int L = lens[b];
    const float* xb = x + (size_t)b * T * CC;

    // init: base-2 log space, shift = a0_hat[0] (uniform across all threads)
    float a0   = (xb[j] + orig[j]) * LOG2E;
    float Mbar = (xb[0] + orig[0]) * LOG2E;
    float q    = __builtin_amdgcn_exp2f(a0 - Mbar);

    float qk = q, Mk = Mbar;  // value kept at t == L-1 (init covers L == 1)

    if (kq == 0) qbuf[0][j] = q;

    // 8-deep x prefetch ring (static indices only)
    float XP[PF];
    #pragma unroll
    for (int u = 0; u < PF; ++u) {
        int tp = 1 + u; if (tp > T - 1) tp = T - 1;
        XP[u] = xb[(size_t)tp * CC + j];
    }

    WG_SYNC();

    // main loop; last chunk overshoots past L (renormalized, results not kept)
    for (int t0 = 1; t0 < L; t0 += PF) {
        #pragma unroll
        for (int u = 0; u < PF; ++u) {
            const int tt = t0 + u;
            const int pb = (tt - 1) & 1, cb = tt & 1;

            float xv = XP[u];                       // 8-step-old load (vmcnt wait)
            int tp = tt + PF; if (tp > T - 1) tp = T - 1;
            XP[u] = xb[(size_t)tp * CC + j];        // refill ring

            const float4* q4 = reinterpret_cast<const float4*>(&qbuf[pb][kq * 16]);
            float q0p = qbuf[pb][0];                // broadcast read, all waves same
            float r   = __builtin_amdgcn_rcpf(q0p); // wave-uniform renorm scale
            float lgr = __builtin_amdgcn_logf(r);   // log2 of ACTUAL scale (exact bookkeeping)
            float exr = __builtin_amdgcn_exp2f(xv * LOG2E) * r;

            float acc0 = 0.f, acc1 = 0.f, acc2 = 0.f, acc3 = 0.f;
            #pragma unroll
            for (int i4 = 0; i4 < 4; ++i4) {
                float4 pv = q4[i4];
                acc0 = fmaf(E[4*i4+0], pv.x, acc0);
                acc1 = fmaf(E[4*i4+1], pv.y, acc1);
                acc2 = fmaf(E[4*i4+2], pv.z, acc2);
                acc3 = fmaf(E[4*i4+3], pv.w, acc3);
            }
            float v = (acc0 + acc1) + (acc2 + acc3); // partial over this k-quarter
            v = pairsum16(v);                        // + partner kq^1   (VALU)
            v = pairsum32(v, l);                     // + partner kq^2   (VALU) -> S[j]

            q = exr * v;
            Mbar -= lgr;
            if (tt == L - 1) { qk = q; Mk = Mbar; }
            if (kq == 0) qbuf[cb][j] = q;

            WG_SYNC();                               // raw: no vmcnt drain
        }
    }

    // alpha[j] at t = L-1; out[b] = sum_j alpha[j]
    float alpha = LN2 * (Mk + __builtin_amdgcn_logf(qk));
    alpha += __shfl_xor(alpha, 1, 64);
    alpha += __shfl_xor(alpha, 2, 64);
    alpha += __shfl_xor(alpha, 4, 64);
    alpha += __shfl_xor(alpha, 8, 64);   // sum over the wave's 16 classes
    if (l == 0) wpart[w] = alpha;
    WG_SYNC();
    if (tid == 0) out[b] = (wpart[0] + wpart[1]) + (wpart[2] + wpart[3]);
}

extern "C" void kernel_launch(void* const* d_in, const int* in_sizes, int n_in,
                              void* d_out, int out_size, void* d_ws, size_t ws_size,
                              hipStream_t stream) {
    const float* x     = (const float*)d_in[0];
    const float* trans = (const float*)d_in[1];
    const float* orig  = (const float*)d_in[2];
    const int*   lens  = (const int*)d_in[3];
    float* out = (float*)d_out;

    const int B = in_sizes[3];
    const int T = in_sizes[0] / (B * CC);

    crf_fwd_kernel<<<B, 256, 0, stream>>>(x, trans, orig, lens, out, T);
}